// Round 3
// baseline (194.939 us; speedup 1.0000x reference)
//
#include <hip/hip_runtime.h>

// Semantics (verified through R0-R9 of previous session):
//   ABI: tokens (N,D) fp32, coords (N,2) int32, weight (D,1,3,3) fp32,
//   straight taps, straight scatter, zero padding/empty cells, bias added,
//   OUTPUT IS (D, N) flat (np advanced indexing, missing .T).
// R12: identical math. Occupancy + MLP push (diagnostic for latency- vs
// EA-throughput-bound):
//   - TPB=64, 512-thread blocks (8 waves) -> 2 blocks/CU, 16 waves/CU.
//   - phase B manually software-pipelined 2-deep: token i+1's 9 float4
//     gathers issued while token i's FMAs run (all indices static).
#define DD 256
#define HH 384
#define WW 384
#define NTOK 65536
#define TPB 64   // tokens per block
#define TPW 8    // tokens per wave

// ---------------------------------------------------------------------------
// Prep: weight (D,9) -> wT (9,D) (straight, no flip); bias copied.
// ---------------------------------------------------------------------------
__global__ __launch_bounds__(256) void prep_kernel(
    const float* __restrict__ weight, const float* __restrict__ bias,
    float* __restrict__ wT, float* __restrict__ biasf)
{
    int ch = threadIdx.x;  // 0..255
    #pragma unroll
    for (int k = 0; k < 9; ++k)
        wT[k * DD + ch] = weight[ch * 9 + k];
    biasf[ch] = bias[ch];
}

// ---------------------------------------------------------------------------
// Scatter (straight): pos_map[r*W + c] = token index (pre-filled with -1)
// ---------------------------------------------------------------------------
__global__ __launch_bounds__(256) void scatter_pos_kernel(
    const int* __restrict__ coords, int* __restrict__ pos_map)
{
    int n = blockIdx.x * blockDim.x + threadIdx.x;
    if (n < NTOK) {
        int r = coords[2 * n + 0];
        int c = coords[2 * n + 1];
        pos_map[r * WW + c] = n;
    }
}

// ---------------------------------------------------------------------------
// Main: 8 waves/block, 8 tokens per wave. Phase A: scalar (SMEM) loads of
// coords + all 72 pos_map entries (wave-uniform addresses). Phase B: 2-deep
// software-pipelined gather+FMA. Epilogue: 64KB LDS transpose; thread
// (ch, half) stores a full 128B line out[ch*N + n0 + half*32 .. +32].
// ---------------------------------------------------------------------------
__global__ __launch_bounds__(512) void conv_gather_kernel(
    const float* __restrict__ tokens,
    const int*   __restrict__ coords,
    const float* __restrict__ wT,      // (9, D)
    const float* __restrict__ biasf,   // (D,)
    const int*   __restrict__ pos_map,
    float*       __restrict__ out)     // (D, N) layout!
{
    __shared__ float s_out[TPB][DD];            // 64 KB

    const int wave = threadIdx.x >> 6;          // 0..7
    const int lane = threadIdx.x & 63;
    const int c0   = lane * 4;
    // wave-uniform first token index, forced into SGPR
    const int nw   = __builtin_amdgcn_readfirstlane(blockIdx.x * TPB + wave * TPW);

    const float4 bias4 = *(const float4*)(biasf + c0);
    float4 w4[9];
    #pragma unroll
    for (int k = 0; k < 9; ++k)
        w4[k] = *(const float4*)(wT + k * DD + c0);

    // ---- Phase A: scalar loads. All addresses wave-uniform -> s_load. ----
    // midx holds token row, or (n | sign bit) when the tap is invalid.
    int midx[TPW][9];
    #pragma unroll
    for (int i = 0; i < TPW; ++i) {
        const int n = nw + i;
        const int r = coords[2 * n + 0];        // uniform -> s_load
        const int c = coords[2 * n + 1];
        #pragma unroll
        for (int dy = 0; dy < 3; ++dy) {
            #pragma unroll
            for (int dx = 0; dx < 3; ++dx) {
                const int k  = dy * 3 + dx;
                const int rr = r + dy - 1;
                const int cc = c + dx - 1;
                const bool in_bounds = (rr >= 0) & (rr < HH) & (cc >= 0) & (cc < WW);
                const int  pidx = in_bounds ? (rr * WW + cc) : 0;
                const int  m    = pos_map[pidx];    // uniform -> s_load
                const bool use  = in_bounds & (m >= 0);
                midx[i][k] = use ? m : (n | 0x80000000);  // self row, sel=0
            }
        }
    }

    // ---- Phase B: 2-deep software-pipelined gathers + FMA. ----
    float4 tbuf[2][9];
    float  sbuf[2][9];
    #pragma unroll
    for (int k = 0; k < 9; ++k) {
        const int mi = midx[0][k];
        tbuf[0][k] = *(const float4*)(tokens + (size_t)(mi & 0x7fffffff) * DD + c0);
        sbuf[0][k] = (mi >= 0) ? 1.0f : 0.0f;
    }
    #pragma unroll
    for (int i = 0; i < TPW; ++i) {
        const int cur = i & 1;
        const int nxt = cur ^ 1;
        if (i + 1 < TPW) {
            #pragma unroll
            for (int k = 0; k < 9; ++k) {
                const int mi = midx[i + 1][k];
                tbuf[nxt][k] = *(const float4*)(tokens + (size_t)(mi & 0x7fffffff) * DD + c0);
                sbuf[nxt][k] = (mi >= 0) ? 1.0f : 0.0f;
            }
        }
        float4 acc = bias4;
        #pragma unroll
        for (int k = 0; k < 9; ++k) {
            const float sel = sbuf[cur][k];
            acc.x += w4[k].x * (sel * tbuf[cur][k].x);
            acc.y += w4[k].y * (sel * tbuf[cur][k].y);
            acc.z += w4[k].z * (sel * tbuf[cur][k].z);
            acc.w += w4[k].w * (sel * tbuf[cur][k].w);
        }
        *(float4*)&s_out[wave * TPW + i][c0] = acc;
    }
    __syncthreads();

    // Thread (ch, half) gathers 32 consecutive tokens for channel ch and
    // stores 128B contiguous at out[ch*N + n0 + half*32].
    const int ch   = threadIdx.x & 255;
    const int half = threadIdx.x >> 8;
    float* dst = out + (size_t)ch * NTOK + blockIdx.x * TPB + half * 32;
    #pragma unroll
    for (int j = 0; j < 8; ++j) {
        float4 v;
        v.x = s_out[half * 32 + 4 * j + 0][ch];
        v.y = s_out[half * 32 + 4 * j + 1][ch];
        v.z = s_out[half * 32 + 4 * j + 2][ch];
        v.w = s_out[half * 32 + 4 * j + 3][ch];
        *(float4*)(dst + 4 * j) = v;
    }
}

// ---------------------------------------------------------------------------
extern "C" void kernel_launch(void* const* d_in, const int* in_sizes, int n_in,
                              void* d_out, int out_size, void* d_ws, size_t ws_size,
                              hipStream_t stream)
{
    const float* tokens = (const float*)d_in[0];
    const int*   coords = (const int*)d_in[1];
    const float* weight = (const float*)d_in[2];
    const float* bias   = (const float*)d_in[3];
    float* out = (float*)d_out;

    // Workspace layout:
    //   [0, 9216)       wT: 9*256 fp32
    //   [9216, 10240)   biasf: 256 fp32
    //   [16384, 606208) pos_map: H*W int32
    char* ws = (char*)d_ws;
    float* wT      = (float*)ws;
    float* biasf   = (float*)(ws + 9216);
    int*   pos_map = (int*)(ws + 16384);

    hipMemsetAsync(pos_map, 0xFF, (size_t)HH * WW * sizeof(int), stream);
    prep_kernel<<<1, 256, 0, stream>>>(weight, bias, wT, biasf);
    scatter_pos_kernel<<<(NTOK + 255) / 256, 256, 0, stream>>>(coords, pos_map);
    conv_gather_kernel<<<NTOK / TPB, 512, 0, stream>>>(tokens, coords, wT, biasf,
                                                       pos_map, out);
}